// Round 1
// baseline (1694.374 us; speedup 1.0000x reference)
//
#include <hip/hip_runtime.h>
#include <hip/hip_bf16.h>
#include <stdint.h>
#include <stddef.h>

// HeadLoraLinear: C = X @ W^T + 2.0 * (X @ A^T) @ B^T
//   X [2048, 2048] fp32, W [65536, 2048] fp32, A [64, 2048] fp32, B [65536, 64] fp32
//   C [2048, 65536] fp32
// Strategy: fold LoRA into the main GEMM by building X' = [bf16(X) | bf16(2*X@A^T)]
// (K' = 2112) in ws, and reading W for k<2048 / lora_B for k>=2048 in the K-loop.
// GEMM is the m97-style 128x128x32 bf16 MFMA structure; B is fp32 in HBM so its
// staging converts fp32->bf16 in registers before ds_write (padded LDS rows).

#define IN_F   2048
#define OUT_F  65536
#define RANK   64
#define M_TOK  2048
#define KP     2112   // 2048 + 64

#define BM 128
#define BN 128
#define BK 32
#define BROW 40       // Bs row stride in bf16 elems (32 data + 8 pad = 80B, 16B aligned)

typedef __attribute__((ext_vector_type(8))) short    short8;
typedef __attribute__((ext_vector_type(4))) float    float4v;
typedef __attribute__((ext_vector_type(4))) unsigned short ushort4v;
typedef __attribute__((ext_vector_type(8))) unsigned short ushort8v;

__device__ __forceinline__ unsigned short f2bf(float f) {
  union { float f; unsigned u; } v; v.f = f;
  return (unsigned short)((v.u + 0x7FFFu + ((v.u >> 16) & 1u)) >> 16);  // RNE
}

__device__ __forceinline__ void gload_lds16(const void* g, void* l) {
  __builtin_amdgcn_global_load_lds(
      (const __attribute__((address_space(1))) unsigned int*)g,
      (__attribute__((address_space(3))) unsigned int*)l, 16, 0, 0);
}

// ---- kernel 1: convert X fp32 -> bf16 into X' cols [0, 2048) --------------
__global__ void cvt_x_kernel(const float* __restrict__ x, unsigned short* __restrict__ xp) {
  const int row = blockIdx.x;
  const int c   = threadIdx.x * 8;
  const float4v* s = (const float4v*)(x + (size_t)row * IN_F + c);
  float4v a = s[0], b = s[1];
  ushort8v o;
  o[0] = f2bf(a.x); o[1] = f2bf(a.y); o[2] = f2bf(a.z); o[3] = f2bf(a.w);
  o[4] = f2bf(b.x); o[5] = f2bf(b.y); o[6] = f2bf(b.z); o[7] = f2bf(b.w);
  *(ushort8v*)(xp + (size_t)row * KP + c) = o;
}

// ---- kernel 2: low = 2 * X @ A^T -> bf16 into X' cols [2048, 2112) --------
// block: 256 thr, 8 rows of X per block; LDS-tiled over K in steps of 128.
__global__ void low_kernel(const float* __restrict__ x, const float* __restrict__ A,
                           unsigned short* __restrict__ xp) {
  __shared__ float xs[128 * 8];    // [k][m] transposed: broadcast reads
  __shared__ float as_[128 * 64];  // [k][r] transposed: conflict-free reads
  const int t  = threadIdx.x;
  const int m0 = blockIdx.x * 8;
  const int r  = t & 63;           // = lane -> conflict-free as_ reads
  const int mg = t >> 6;           // wave id -> xs reads broadcast within wave
  float acc0 = 0.f, acc1 = 0.f;
  for (int k0 = 0; k0 < IN_F; k0 += 128) {
    __syncthreads();
    {
      const int m = t >> 5, kq = (t & 31) * 4;
      float4v v = *(const float4v*)(x + (size_t)(m0 + m) * IN_F + k0 + kq);
      xs[(kq + 0) * 8 + m] = v.x; xs[(kq + 1) * 8 + m] = v.y;
      xs[(kq + 2) * 8 + m] = v.z; xs[(kq + 3) * 8 + m] = v.w;
    }
#pragma unroll
    for (int j = 0; j < 8; ++j) {
      const int f = t + 256 * j;
      const int rr = f >> 5, q = f & 31;
      float4v v = *(const float4v*)(A + (size_t)rr * IN_F + k0 + q * 4);
      as_[(q * 4 + 0) * 64 + rr] = v.x; as_[(q * 4 + 1) * 64 + rr] = v.y;
      as_[(q * 4 + 2) * 64 + rr] = v.z; as_[(q * 4 + 3) * 64 + rr] = v.w;
    }
    __syncthreads();
    const int ma = mg * 2;
#pragma unroll 8
    for (int k = 0; k < 128; ++k) {
      float a = as_[k * 64 + r];
      acc0 += a * xs[k * 8 + ma];
      acc1 += a * xs[k * 8 + ma + 1];
    }
  }
  const int ma = mg * 2;
  xp[(size_t)(m0 + ma) * KP + IN_F + r]     = f2bf(2.0f * acc0);
  xp[(size_t)(m0 + ma + 1) * KP + IN_F + r] = f2bf(2.0f * acc1);
}

// ---- kernel 3: main GEMM, bf16 MFMA, K' = 2112 ----------------------------
// 256 thr = 4 waves (2x2), each wave 64x64 = 4x4 tiles of 16x16x32 MFMA.
__global__ void gemm_kernel(const unsigned short* __restrict__ xp,
                            const float* __restrict__ W,
                            const float* __restrict__ Bl,
                            float* __restrict__ C) {
  __shared__ __align__(16) unsigned short As[BM * BK];    // 8 KB, 64B rows (global_load_lds layout)
  __shared__ __align__(16) unsigned short Bs[BN * BROW];  // 10 KB, padded 80B rows

  const int t    = threadIdx.x;
  const int lane = t & 63;
  const int wid  = t >> 6;
  const int wr   = wid >> 1;   // wave row (0..1)
  const int wc   = wid & 1;    // wave col (0..1)
  const int tm   = lane & 15;
  const int quad = lane >> 4;

  const int m0 = blockIdx.x * BM;   // 16 m-tiles, fastest-varying: share B slab in L3
  const int n0 = blockIdx.y * BN;   // 512 n-tiles

  float4v acc[4][4] = {};

  for (int k0 = 0; k0 < KP; k0 += BK) {
    __syncthreads();  // previous iteration's frag reads complete before overwrite
    // --- stage A (bf16, 8 KB): async global->LDS, 16B/lane, wave-contiguous ---
    {
      const int f0 = t, f1 = t + 256;
      gload_lds16(xp + (size_t)(m0 + (f0 >> 2)) * KP + k0 + (f0 & 3) * 8, &As[f0 * 8]);
      gload_lds16(xp + (size_t)(m0 + (f1 >> 2)) * KP + k0 + (f1 & 3) * 8, &As[f1 * 8]);
    }
    // --- stage B (fp32 -> bf16, 16 KB read, 8 KB written) ---
    const float* Bsrc; int rstride, kk;
    if (k0 < IN_F) { Bsrc = W;  rstride = IN_F; kk = k0; }
    else           { Bsrc = Bl; rstride = RANK; kk = k0 - IN_F; }
#pragma unroll
    for (int j = 0; j < 4; ++j) {
      const int f = t + 256 * j;
      const int row = f >> 3, seg = f & 7;
      float4v v = *(const float4v*)(Bsrc + (size_t)(n0 + row) * rstride + kk + seg * 4);
      ushort4v o;
      o.x = f2bf(v.x); o.y = f2bf(v.y); o.z = f2bf(v.z); o.w = f2bf(v.w);
      *(ushort4v*)&Bs[row * BROW + seg * 4] = o;
    }
    __syncthreads();
    // --- fragments + 16 MFMA per wave ---
    short8 af[4], bfr[4];
#pragma unroll
    for (int i = 0; i < 4; ++i)
      af[i] = *(const short8*)&As[(wr * 64 + i * 16 + tm) * BK + quad * 8];
#pragma unroll
    for (int i = 0; i < 4; ++i)
      bfr[i] = *(const short8*)&Bs[(wc * 64 + i * 16 + tm) * BROW + quad * 8];
#pragma unroll
    for (int i = 0; i < 4; ++i)
#pragma unroll
      for (int jn = 0; jn < 4; ++jn)
        acc[i][jn] = __builtin_amdgcn_mfma_f32_16x16x32_bf16(af[i], bfr[jn], acc[i][jn], 0, 0, 0);
  }

  // --- epilogue: C/D layout col = lane&15, row = quad*4 + reg (m89-verified) ---
#pragma unroll
  for (int i = 0; i < 4; ++i) {
    const int mrow = m0 + wr * 64 + i * 16 + quad * 4;
#pragma unroll
    for (int jn = 0; jn < 4; ++jn) {
      const int ncol = n0 + wc * 64 + jn * 16 + tm;
      float4v v = acc[i][jn];
      C[(size_t)(mrow + 0) * OUT_F + ncol] = v.x;
      C[(size_t)(mrow + 1) * OUT_F + ncol] = v.y;
      C[(size_t)(mrow + 2) * OUT_F + ncol] = v.z;
      C[(size_t)(mrow + 3) * OUT_F + ncol] = v.w;
    }
  }
}

extern "C" void kernel_launch(void* const* d_in, const int* in_sizes, int n_in,
                              void* d_out, int out_size, void* d_ws, size_t ws_size,
                              hipStream_t stream) {
  const float* x  = (const float*)d_in[0];
  const float* W  = (const float*)d_in[1];
  const float* lA = (const float*)d_in[2];
  const float* lB = (const float*)d_in[3];
  float* out = (float*)d_out;
  unsigned short* xp = (unsigned short*)d_ws;  // X' [2048, 2112] bf16 = 8.65 MB

  hipLaunchKernelGGL(cvt_x_kernel, dim3(M_TOK), dim3(256), 0, stream, x, xp);
  hipLaunchKernelGGL(low_kernel, dim3(M_TOK / 8), dim3(256), 0, stream, x, lA, xp);
  hipLaunchKernelGGL(gemm_kernel, dim3(M_TOK / BM, OUT_F / BN), dim3(256), 0, stream,
                     xp, W, lB, out);
}